// Round 1
// baseline (761.873 us; speedup 1.0000x reference)
//
#include <hip/hip_runtime.h>
#include <math.h>

#define N_NODES 50000
#define N_EDGES 800000
#define ET (N_EDGES + N_NODES)   // 850000 edges incl. self-loops
#define D 256
#define NEG_SLOPE 0.2f
#define SCAN_ITEMS 1024
#define NB_SCAN ((N_NODES + SCAN_ITEMS - 1) / SCAN_ITEMS)   // 49

// ---------------- edge format probe ----------------
// Harness may hand edge_index as int32 or raw int64. If int64 (little-endian),
// every odd int32 word is a zero high-word. Random src values make all-zero
// odd words impossible for genuine int32 data.
__global__ void detect_fmt(const int* __restrict__ eidx, int* __restrict__ flag) {
    int i = blockIdx.x * 256 + threadIdx.x;     // sample first 1024 odd words
    if (i < 1024 && eidx[2 * i + 1] != 0) atomicOr(flag, 1);  // nonzero -> int32
}

__device__ inline int edge_src(const int* eidx, int is32, int e) {
    if (e >= N_EDGES) return e - N_EDGES;
    return is32 ? eidx[e] : eidx[2 * e];
}
__device__ inline int edge_dst(const int* eidx, int is32, int e) {
    if (e >= N_EDGES) return e - N_EDGES;
    return is32 ? eidx[N_EDGES + e] : eidx[2 * (N_EDGES + e)];
}

// ---------------- CSR build ----------------
__global__ void count_deg(const int* __restrict__ eidx, const int* __restrict__ flag,
                          int* __restrict__ deg) {
    int e = blockIdx.x * 256 + threadIdx.x;
    if (e >= ET) return;
    int is32 = *flag;
    atomicAdd(&deg[edge_dst(eidx, is32, e)], 1);
}

__global__ __launch_bounds__(256) void scan_block_sums(const int* __restrict__ deg,
                                                       int* __restrict__ bsum) {
    __shared__ int wsums[4];
    int base = blockIdx.x * SCAN_ITEMS + threadIdx.x * 4;
    int s = 0;
    #pragma unroll
    for (int k = 0; k < 4; ++k) { int i = base + k; if (i < N_NODES) s += deg[i]; }
    for (int d = 1; d < 64; d <<= 1) s += __shfl_xor(s, d, 64);
    int lane = threadIdx.x & 63, wid = threadIdx.x >> 6;
    if (lane == 0) wsums[wid] = s;
    __syncthreads();
    if (threadIdx.x == 0) bsum[blockIdx.x] = wsums[0] + wsums[1] + wsums[2] + wsums[3];
}

__global__ void scan_carry(const int* __restrict__ bsum, int* __restrict__ carry,
                           int* __restrict__ off) {
    if (threadIdx.x == 0) {
        int run = 0;
        for (int b = 0; b < NB_SCAN; ++b) { carry[b] = run; run += bsum[b]; }
        off[N_NODES] = ET;
    }
}

__global__ __launch_bounds__(256) void scan_write(const int* __restrict__ deg,
                                                  const int* __restrict__ carry,
                                                  int* __restrict__ off,
                                                  int* __restrict__ cur) {
    __shared__ int wsums[4];
    int base = blockIdx.x * SCAN_ITEMS + threadIdx.x * 4;
    int v[4]; int s = 0;
    #pragma unroll
    for (int k = 0; k < 4; ++k) { int i = base + k; v[k] = (i < N_NODES) ? deg[i] : 0; s += v[k]; }
    int inc = s;
    int lane = threadIdx.x & 63, wid = threadIdx.x >> 6;
    for (int d = 1; d < 64; d <<= 1) { int u = __shfl_up(inc, d, 64); if (lane >= d) inc += u; }
    if (lane == 63) wsums[wid] = inc;
    __syncthreads();
    int woff = 0;
    for (int w = 0; w < wid; ++w) woff += wsums[w];
    int excl = woff + inc - s + carry[blockIdx.x];
    #pragma unroll
    for (int k = 0; k < 4; ++k) {
        int i = base + k;
        if (i < N_NODES) { off[i] = excl; cur[i] = excl; excl += v[k]; }
    }
}

__global__ void scatter_edges(const int* __restrict__ eidx, const int* __restrict__ flag,
                              int* __restrict__ cur, int* __restrict__ srcs) {
    int e = blockIdx.x * 256 + threadIdx.x;
    if (e >= ET) return;
    int is32 = *flag;
    int src = edge_src(eidx, is32, e);
    int dst = edge_dst(eidx, is32, e);
    int pos = atomicAdd(&cur[dst], 1);
    srcs[pos] = src;
}

// ---------------- fp32 GEMM: C[M x 256] = A[M x K] * B[K x 256] ----------------
__global__ __launch_bounds__(256) void gemm_f32(const float* __restrict__ A,
                                                const float* __restrict__ B,
                                                float* __restrict__ C,
                                                int M, int K) {
    __shared__ float As[32][68];   // [k][row], stride 68 keeps float4 align + spreads banks
    __shared__ float Bs[32][64];   // [k][col]
    int tx = threadIdx.x & 15;     // col group (4 cols each)
    int ty = threadIdx.x >> 4;     // row group (4 rows each)
    int row0 = blockIdx.y * 64;
    int col0 = blockIdx.x * 64;
    float acc[4][4] = {};
    for (int k0 = 0; k0 < K; k0 += 32) {
        int kk = threadIdx.x & 31, rr = threadIdx.x >> 5;
        #pragma unroll
        for (int p = 0; p < 8; ++p) {
            int r = rr + p * 8;
            int grow = row0 + r;
            As[kk][r] = (grow < M) ? A[(size_t)grow * K + k0 + kk] : 0.f;
        }
        int cc = threadIdx.x & 63, kb = threadIdx.x >> 6;
        #pragma unroll
        for (int p = 0; p < 8; ++p) {
            int k = kb + p * 4;
            Bs[k][cc] = B[(size_t)(k0 + k) * D + col0 + cc];
        }
        __syncthreads();
        #pragma unroll
        for (int k = 0; k < 32; ++k) {
            float4 a = *(const float4*)&As[k][ty * 4];
            float4 b = *(const float4*)&Bs[k][tx * 4];
            acc[0][0] += a.x * b.x; acc[0][1] += a.x * b.y; acc[0][2] += a.x * b.z; acc[0][3] += a.x * b.w;
            acc[1][0] += a.y * b.x; acc[1][1] += a.y * b.y; acc[1][2] += a.y * b.z; acc[1][3] += a.y * b.w;
            acc[2][0] += a.z * b.x; acc[2][1] += a.z * b.y; acc[2][2] += a.z * b.z; acc[2][3] += a.z * b.w;
            acc[3][0] += a.w * b.x; acc[3][1] += a.w * b.y; acc[3][2] += a.w * b.z; acc[3][3] += a.w * b.w;
        }
        __syncthreads();
    }
    #pragma unroll
    for (int i = 0; i < 4; ++i) {
        int grow = row0 + ty * 4 + i;
        if (grow < M) {
            float4 v = make_float4(acc[i][0], acc[i][1], acc[i][2], acc[i][3]);
            *(float4*)&C[(size_t)grow * D + col0 + tx * 4] = v;
        }
    }
}

// ---------------- attention scores: es[n,h] = <h_row, a_src>, ed likewise ----------------
template <int HEADS>
__global__ __launch_bounds__(256) void attn_scores(const float* __restrict__ h,
                                                   const float* __restrict__ a_src,
                                                   const float* __restrict__ a_dst,
                                                   float* __restrict__ es,
                                                   float* __restrict__ ed) {
    int node = blockIdx.x * 4 + (threadIdx.x >> 6);
    int lane = threadIdx.x & 63;
    if (node >= N_NODES) return;
    float4 v  = *(const float4*)&h[(size_t)node * D + lane * 4];
    float4 as = *(const float4*)&a_src[lane * 4];
    float4 ad = *(const float4*)&a_dst[lane * 4];
    float ps = v.x * as.x + v.y * as.y + v.z * as.z + v.w * as.w;
    float pd = v.x * ad.x + v.y * ad.y + v.z * ad.z + v.w * ad.w;
    const int GS = 64 / HEADS;           // lanes per head
    #pragma unroll
    for (int d2 = 1; d2 < GS; d2 <<= 1) {
        ps += __shfl_xor(ps, d2, 64);
        pd += __shfl_xor(pd, d2, 64);
    }
    if ((lane & (GS - 1)) == 0) {
        int hd = lane / GS;
        es[(size_t)node * HEADS + hd] = ps;
        ed[(size_t)node * HEADS + hd] = pd;
    }
}

// ---------------- GAT aggregation, H=8 heads x 32 ch, elu fused ----------------
__global__ __launch_bounds__(256) void aggregate_h8(const float* __restrict__ h,
                                                    const float* __restrict__ es,
                                                    const float* __restrict__ ed,
                                                    const int* __restrict__ off,
                                                    const int* __restrict__ srcs,
                                                    const float* __restrict__ bias,
                                                    float* __restrict__ out) {
    int n = blockIdx.x;
    int t = threadIdx.x;           // output channel
    int hd = t >> 5;               // head
    int g  = t & 31;
    int begin = off[n], end = off[n + 1];
    float edn = ed[n * 8 + hd];
    // segment max (32 threads per head, strided over edges)
    float m = -1e30f;
    for (int i = begin + g; i < end; i += 32) {
        float e = es[srcs[i] * 8 + hd] + edn;
        e = e > 0.f ? e : NEG_SLOPE * e;
        m = fmaxf(m, e);
    }
    #pragma unroll
    for (int d2 = 1; d2 < 32; d2 <<= 1) m = fmaxf(m, __shfl_xor(m, d2, 64));
    // segment sum of exp
    float ssum = 0.f;
    for (int i = begin + g; i < end; i += 32) {
        float e = es[srcs[i] * 8 + hd] + edn;
        e = e > 0.f ? e : NEG_SLOPE * e;
        ssum += __expf(e - m);
    }
    #pragma unroll
    for (int d2 = 1; d2 < 32; d2 <<= 1) ssum += __shfl_xor(ssum, d2, 64);
    float inv_s = 1.f / ssum;
    // weighted gather
    float acc = 0.f;
    for (int i = begin; i < end; ++i) {
        int s = srcs[i];
        float e = es[s * 8 + hd] + edn;
        e = e > 0.f ? e : NEG_SLOPE * e;
        float p = __expf(e - m) * inv_s;
        acc += h[(size_t)s * D + t] * p;
    }
    float r = acc + bias[t];
    out[(size_t)n * D + t] = r > 0.f ? r : __expf(r) - 1.f;   // elu
}

// ---------------- GAT aggregation, H=1 head x 256 ch, elu fused ----------------
__global__ __launch_bounds__(256) void aggregate_h1(const float* __restrict__ h,
                                                    const float* __restrict__ es,
                                                    const float* __restrict__ ed,
                                                    const int* __restrict__ off,
                                                    const int* __restrict__ srcs,
                                                    const float* __restrict__ bias,
                                                    float* __restrict__ out) {
    int n = blockIdx.x;
    int t = threadIdx.x;
    int begin = off[n], end = off[n + 1];
    float edn = ed[n];
    __shared__ float red[4];
    int lane = t & 63, wid = t >> 6;
    // segment max across block
    float m = -1e30f;
    for (int i = begin + t; i < end; i += 256) {
        float e = es[srcs[i]] + edn;
        e = e > 0.f ? e : NEG_SLOPE * e;
        m = fmaxf(m, e);
    }
    #pragma unroll
    for (int d2 = 1; d2 < 64; d2 <<= 1) m = fmaxf(m, __shfl_xor(m, d2, 64));
    if (lane == 0) red[wid] = m;
    __syncthreads();
    m = fmaxf(fmaxf(red[0], red[1]), fmaxf(red[2], red[3]));
    __syncthreads();
    // segment sum across block
    float ssum = 0.f;
    for (int i = begin + t; i < end; i += 256) {
        float e = es[srcs[i]] + edn;
        e = e > 0.f ? e : NEG_SLOPE * e;
        ssum += __expf(e - m);
    }
    #pragma unroll
    for (int d2 = 1; d2 < 64; d2 <<= 1) ssum += __shfl_xor(ssum, d2, 64);
    if (lane == 0) red[wid] = ssum;
    __syncthreads();
    float inv_s = 1.f / (red[0] + red[1] + red[2] + red[3]);
    // weighted gather
    float acc = 0.f;
    for (int i = begin; i < end; ++i) {
        int s = srcs[i];
        float e = es[s] + edn;
        e = e > 0.f ? e : NEG_SLOPE * e;
        float p = __expf(e - m) * inv_s;
        acc += h[(size_t)s * D + t] * p;
    }
    float r = acc + bias[t];
    out[(size_t)n * D + t] = r > 0.f ? r : __expf(r) - 1.f;   // elu
}

// ---------------- launch ----------------
extern "C" void kernel_launch(void* const* d_in, const int* in_sizes, int n_in,
                              void* d_out, int out_size, void* d_ws, size_t ws_size,
                              hipStream_t stream) {
    const float* x        = (const float*)d_in[0];
    const int*   eidx     = (const int*)d_in[1];
    const float* W1       = (const float*)d_in[2];
    const float* att_src1 = (const float*)d_in[3];
    const float* att_dst1 = (const float*)d_in[4];
    const float* b1       = (const float*)d_in[5];
    const float* W2       = (const float*)d_in[6];
    const float* att_src2 = (const float*)d_in[7];
    const float* att_dst2 = (const float*)d_in[8];
    const float* b2       = (const float*)d_in[9];
    float* out = (float*)d_out;

    char* ws = (char*)d_ws;
    size_t o = 0;
    auto take = [&](size_t bytes) { char* p = ws + o; o = (o + bytes + 255) & ~(size_t)255; return p; };
    float* h1   = (float*)take((size_t)N_NODES * D * 4);   // also reused as h2
    float* z    = (float*)take((size_t)N_NODES * D * 4);
    float* es1  = (float*)take((size_t)N_NODES * 8 * 4);
    float* ed1  = (float*)take((size_t)N_NODES * 8 * 4);
    float* es2  = (float*)take((size_t)N_NODES * 4);
    float* ed2  = (float*)take((size_t)N_NODES * 4);
    int*   off  = (int*)take((size_t)(N_NODES + 1) * 4);
    int*   cur  = (int*)take((size_t)N_NODES * 4);
    int*   srcs = (int*)take((size_t)ET * 4);
    int*   deg  = (int*)take((size_t)N_NODES * 4);
    int*   bsum = (int*)take(256);
    int*   carry= (int*)take(256);
    int*   flag = (int*)take(256);

    // zero the counters each call (ws is not re-poisoned but we must not rely on old state)
    hipMemsetAsync(deg, 0, (size_t)N_NODES * 4, stream);
    hipMemsetAsync(flag, 0, 4, stream);

    const int EB = (ET + 255) / 256;
    detect_fmt<<<4, 256, 0, stream>>>(eidx, flag);
    count_deg<<<EB, 256, 0, stream>>>(eidx, flag, deg);
    scan_block_sums<<<NB_SCAN, 256, 0, stream>>>(deg, bsum);
    scan_carry<<<1, 64, 0, stream>>>(bsum, carry, off);
    scan_write<<<NB_SCAN, 256, 0, stream>>>(deg, carry, off, cur);
    scatter_edges<<<EB, 256, 0, stream>>>(eidx, flag, cur, srcs);

    dim3 ggrid(4, (N_NODES + 63) / 64);
    // layer 1
    gemm_f32<<<ggrid, 256, 0, stream>>>(x, W1, h1, N_NODES, 128);
    attn_scores<8><<<(N_NODES + 3) / 4, 256, 0, stream>>>(h1, att_src1, att_dst1, es1, ed1);
    aggregate_h8<<<N_NODES, 256, 0, stream>>>(h1, es1, ed1, off, srcs, b1, z);
    // layer 2 (h2 reuses h1 buffer)
    gemm_f32<<<ggrid, 256, 0, stream>>>(z, W2, h1, N_NODES, 256);
    attn_scores<1><<<(N_NODES + 3) / 4, 256, 0, stream>>>(h1, att_src2, att_dst2, es2, ed2);
    aggregate_h1<<<N_NODES, 256, 0, stream>>>(h1, es2, ed2, off, srcs, b2, out);
}

// Round 2
// 465.177 us; speedup vs baseline: 1.6378x; 1.6378x over previous
//
#include <hip/hip_runtime.h>
#include <math.h>

#define N_NODES 50000
#define N_EDGES 800000
#define ET (N_EDGES + N_NODES)   // 850000 edges incl. self-loops
#define D 256
#define NEG_SLOPE 0.2f
#define SCAN_ITEMS 1024
#define NB_SCAN ((N_NODES + SCAN_ITEMS - 1) / SCAN_ITEMS)   // 49

typedef __attribute__((ext_vector_type(8))) short bf16x8;       // MFMA A/B frag (8 bf16)
typedef __attribute__((ext_vector_type(8))) unsigned short ushort8;
typedef __attribute__((ext_vector_type(4))) unsigned short us4;
typedef __attribute__((ext_vector_type(4))) float f32x4;

__device__ inline unsigned short f2bf(float f) {
    union { float f; unsigned u; } v; v.f = f;
    return (unsigned short)((v.u + 0x7FFFu + ((v.u >> 16) & 1u)) >> 16);
}

// ---------------- edge format probe (int32 vs int64 edge_index) ----------------
__global__ void detect_fmt(const int* __restrict__ eidx, int* __restrict__ flag) {
    int i = blockIdx.x * 256 + threadIdx.x;
    if (i < 1024 && eidx[2 * i + 1] != 0) atomicOr(flag, 1);  // nonzero odd word -> int32
}

__device__ inline int edge_src(const int* eidx, int is32, int e) {
    if (e >= N_EDGES) return e - N_EDGES;
    return is32 ? eidx[e] : eidx[2 * e];
}
__device__ inline int edge_dst(const int* eidx, int is32, int e) {
    if (e >= N_EDGES) return e - N_EDGES;
    return is32 ? eidx[N_EDGES + e] : eidx[2 * (N_EDGES + e)];
}

// ---------------- CSR build ----------------
__global__ void count_deg(const int* __restrict__ eidx, const int* __restrict__ flag,
                          int* __restrict__ deg) {
    int e = blockIdx.x * 256 + threadIdx.x;
    if (e >= ET) return;
    int is32 = *flag;
    atomicAdd(&deg[edge_dst(eidx, is32, e)], 1);
}

__global__ __launch_bounds__(256) void scan_block_sums(const int* __restrict__ deg,
                                                       int* __restrict__ bsum) {
    __shared__ int wsums[4];
    int base = blockIdx.x * SCAN_ITEMS + threadIdx.x * 4;
    int s = 0;
    #pragma unroll
    for (int k = 0; k < 4; ++k) { int i = base + k; if (i < N_NODES) s += deg[i]; }
    for (int d = 1; d < 64; d <<= 1) s += __shfl_xor(s, d, 64);
    int lane = threadIdx.x & 63, wid = threadIdx.x >> 6;
    if (lane == 0) wsums[wid] = s;
    __syncthreads();
    if (threadIdx.x == 0) bsum[blockIdx.x] = wsums[0] + wsums[1] + wsums[2] + wsums[3];
}

__global__ void scan_carry(const int* __restrict__ bsum, int* __restrict__ carry,
                           int* __restrict__ off) {
    if (threadIdx.x == 0) {
        int run = 0;
        for (int b = 0; b < NB_SCAN; ++b) { carry[b] = run; run += bsum[b]; }
        off[N_NODES] = ET;
    }
}

__global__ __launch_bounds__(256) void scan_write(const int* __restrict__ deg,
                                                  const int* __restrict__ carry,
                                                  int* __restrict__ off,
                                                  int* __restrict__ cur) {
    __shared__ int wsums[4];
    int base = blockIdx.x * SCAN_ITEMS + threadIdx.x * 4;
    int v[4]; int s = 0;
    #pragma unroll
    for (int k = 0; k < 4; ++k) { int i = base + k; v[k] = (i < N_NODES) ? deg[i] : 0; s += v[k]; }
    int inc = s;
    int lane = threadIdx.x & 63, wid = threadIdx.x >> 6;
    for (int d = 1; d < 64; d <<= 1) { int u = __shfl_up(inc, d, 64); if (lane >= d) inc += u; }
    if (lane == 63) wsums[wid] = inc;
    __syncthreads();
    int woff = 0;
    for (int w = 0; w < wid; ++w) woff += wsums[w];
    int excl = woff + inc - s + carry[blockIdx.x];
    #pragma unroll
    for (int k = 0; k < 4; ++k) {
        int i = base + k;
        if (i < N_NODES) { off[i] = excl; cur[i] = excl; excl += v[k]; }
    }
}

__global__ void scatter_edges(const int* __restrict__ eidx, const int* __restrict__ flag,
                              int* __restrict__ cur, int* __restrict__ srcs) {
    int e = blockIdx.x * 256 + threadIdx.x;
    if (e >= ET) return;
    int is32 = *flag;
    int src = edge_src(eidx, is32, e);
    int dst = edge_dst(eidx, is32, e);
    int pos = atomicAdd(&cur[dst], 1);
    srcs[pos] = src;
}

// ---------------- conversions ----------------
__global__ __launch_bounds__(256) void conv_f32_bf16(const float* __restrict__ in,
                                                     unsigned short* __restrict__ outb,
                                                     int n4) {
    int i = blockIdx.x * 256 + threadIdx.x;
    if (i >= n4) return;
    float4 v = *(const float4*)&in[(size_t)i * 4];
    us4 o; o.x = f2bf(v.x); o.y = f2bf(v.y); o.z = f2bf(v.z); o.w = f2bf(v.w);
    *(us4*)&outb[(size_t)i * 4] = o;
}

// W[K][256] -> Wt[256][K] bf16
__global__ void conv_w_t(const float* __restrict__ W, unsigned short* __restrict__ Wt, int K) {
    int k = blockIdx.x, n = threadIdx.x;
    Wt[(size_t)n * K + k] = f2bf(W[(size_t)k * D + n]);
}

// ---------------- bf16 MFMA GEMM: C[M x 256] = A[M x K] * Bt^T  (Bt is [256][K]) ----------------
__global__ __launch_bounds__(256) void gemm_bf16(const unsigned short* __restrict__ A,
                                                 const unsigned short* __restrict__ Bt,
                                                 float* __restrict__ C, int M, int K) {
    __shared__ __align__(16) unsigned short As[128][40];  // [row][k], pad to 40 for banks
    __shared__ __align__(16) unsigned short Bs[64][40];   // [n][k]
    int t = threadIdx.x, lane = t & 63, wid = t >> 6;
    int wm = wid >> 1, wn = wid & 1;                      // 2x2 waves, wave tile 64x32
    int row0 = blockIdx.y * 128, col0 = blockIdx.x * 64;
    f32x4 acc[4][2] = {};
    int ar = t >> 1, ap = t & 1;                          // A: 2 thr/row, 32B each
    int bn = t >> 2, bp = t & 3;                          // B: 4 thr/row, 16B each
    for (int k0 = 0; k0 < K; k0 += 32) {
        ushort8 a0 = {0,0,0,0,0,0,0,0}, a1 = {0,0,0,0,0,0,0,0};
        if (row0 + ar < M) {
            const ushort8* p = (const ushort8*)&A[(size_t)(row0 + ar) * K + k0 + ap * 16];
            a0 = p[0]; a1 = p[1];
        }
        *(ushort8*)&As[ar][ap * 16]     = a0;
        *(ushort8*)&As[ar][ap * 16 + 8] = a1;
        *(ushort8*)&Bs[bn][bp * 8] = *(const ushort8*)&Bt[(size_t)(col0 + bn) * K + k0 + bp * 8];
        __syncthreads();
        bf16x8 af[4], bg[2];
        #pragma unroll
        for (int mi = 0; mi < 4; ++mi)
            af[mi] = *(const bf16x8*)&As[wm * 64 + mi * 16 + (lane & 15)][(lane >> 4) * 8];
        #pragma unroll
        for (int ni = 0; ni < 2; ++ni)
            bg[ni] = *(const bf16x8*)&Bs[wn * 32 + ni * 16 + (lane & 15)][(lane >> 4) * 8];
        #pragma unroll
        for (int mi = 0; mi < 4; ++mi)
            #pragma unroll
            for (int ni = 0; ni < 2; ++ni)
                acc[mi][ni] = __builtin_amdgcn_mfma_f32_16x16x32_bf16(af[mi], bg[ni], acc[mi][ni], 0, 0, 0);
        __syncthreads();
    }
    #pragma unroll
    for (int mi = 0; mi < 4; ++mi) {
        int rowb = row0 + wm * 64 + mi * 16 + ((lane >> 4) << 2);
        #pragma unroll
        for (int ni = 0; ni < 2; ++ni) {
            int col = col0 + wn * 32 + ni * 16 + (lane & 15);
            #pragma unroll
            for (int r = 0; r < 4; ++r)
                if (rowb + r < M) C[(size_t)(rowb + r) * D + col] = acc[mi][ni][r];
        }
    }
}

// ---------------- attention scores: es[n,h] = <h_row, a_src>, ed likewise ----------------
template <int HEADS>
__global__ __launch_bounds__(256) void attn_scores(const float* __restrict__ h,
                                                   const float* __restrict__ a_src,
                                                   const float* __restrict__ a_dst,
                                                   float* __restrict__ es,
                                                   float* __restrict__ ed) {
    int node = blockIdx.x * 4 + (threadIdx.x >> 6);
    int lane = threadIdx.x & 63;
    if (node >= N_NODES) return;
    float4 v  = *(const float4*)&h[(size_t)node * D + lane * 4];
    float4 as = *(const float4*)&a_src[lane * 4];
    float4 ad = *(const float4*)&a_dst[lane * 4];
    float ps = v.x * as.x + v.y * as.y + v.z * as.z + v.w * as.w;
    float pd = v.x * ad.x + v.y * ad.y + v.z * ad.z + v.w * ad.w;
    const int GS = 64 / HEADS;
    #pragma unroll
    for (int d2 = 1; d2 < GS; d2 <<= 1) {
        ps += __shfl_xor(ps, d2, 64);
        pd += __shfl_xor(pd, d2, 64);
    }
    if ((lane & (GS - 1)) == 0) {
        int hd = lane / GS;
        es[(size_t)node * HEADS + hd] = ps;
        ed[(size_t)node * HEADS + hd] = pd;
    }
}

// ---------------- per-edge alpha via online softmax; one wave per node ----------------
template <int H>
__global__ __launch_bounds__(256) void softmax_alpha(const float* __restrict__ es,
                                                     const float* __restrict__ ed,
                                                     const int* __restrict__ off,
                                                     const int* __restrict__ srcs,
                                                     float* __restrict__ alpha) {
    int n = blockIdx.x * 4 + (threadIdx.x >> 6);
    if (n >= N_NODES) return;
    int lane = threadIdx.x & 63;
    int begin = off[n], end = off[n + 1];
    int j  = (H == 8) ? (lane >> 3) : lane;
    int hd = (H == 8) ? (lane & 7) : 0;
    const int JS = (H == 8) ? 8 : 64;
    float edn = ed[(size_t)n * H + hd];
    // online (max, sum) over this lane's edge stripe
    float m = -1e30f, s = 0.f;
    for (int i = begin + j; i < end; i += JS) {
        float e = es[(size_t)srcs[i] * H + hd] + edn;
        e = e > 0.f ? e : NEG_SLOPE * e;
        float nm = fmaxf(m, e);
        s = s * __expf(m - nm) + __expf(e - nm);
        m = nm;
    }
    // combine lanes with same head (xor over j bits)
    #pragma unroll
    for (int mask = (H == 8) ? 8 : 1; mask < 64; mask <<= 1) {
        float om = __shfl_xor(m, mask, 64);
        float os = __shfl_xor(s, mask, 64);
        float nm = fmaxf(m, om);
        s = s * __expf(m - nm) + os * __expf(om - nm);
        m = nm;
    }
    float inv_s = 1.f / s;
    // write per-edge alpha (coalesced)
    for (int i = begin + j; i < end; i += JS) {
        float e = es[(size_t)srcs[i] * H + hd] + edn;
        e = e > 0.f ? e : NEG_SLOPE * e;
        alpha[(size_t)i * H + hd] = __expf(e - m) * inv_s;
    }
}

// ---------------- weighted gather + bias + elu; one wave per node, float4/lane ----------------
template <int H, bool OUT_BF16>
__global__ __launch_bounds__(256) void gather_agg(const float* __restrict__ h,
                                                  const float* __restrict__ alpha,
                                                  const int* __restrict__ off,
                                                  const int* __restrict__ srcs,
                                                  const float* __restrict__ bias,
                                                  void* __restrict__ outv) {
    int n = blockIdx.x * 4 + (threadIdx.x >> 6);
    if (n >= N_NODES) return;
    int lane = threadIdx.x & 63;
    int begin = off[n], end = off[n + 1];
    int hsel = (H == 8) ? (lane >> 3) : 0;
    float ax = 0.f, ay = 0.f, az = 0.f, aw = 0.f;
    int i = begin;
    for (; i + 1 < end; i += 2) {
        int s0 = srcs[i], s1 = srcs[i + 1];
        float al0 = alpha[(size_t)i * H + hsel];
        float al1 = alpha[(size_t)(i + 1) * H + hsel];
        float4 h0 = *(const float4*)&h[(size_t)s0 * D + lane * 4];
        float4 h1 = *(const float4*)&h[(size_t)s1 * D + lane * 4];
        ax += h0.x * al0 + h1.x * al1;
        ay += h0.y * al0 + h1.y * al1;
        az += h0.z * al0 + h1.z * al1;
        aw += h0.w * al0 + h1.w * al1;
    }
    if (i < end) {
        int s0 = srcs[i];
        float al0 = alpha[(size_t)i * H + hsel];
        float4 h0 = *(const float4*)&h[(size_t)s0 * D + lane * 4];
        ax += h0.x * al0; ay += h0.y * al0; az += h0.z * al0; aw += h0.w * al0;
    }
    float4 b = *(const float4*)&bias[lane * 4];
    float r0 = ax + b.x, r1 = ay + b.y, r2 = az + b.z, r3 = aw + b.w;
    r0 = r0 > 0.f ? r0 : __expf(r0) - 1.f;
    r1 = r1 > 0.f ? r1 : __expf(r1) - 1.f;
    r2 = r2 > 0.f ? r2 : __expf(r2) - 1.f;
    r3 = r3 > 0.f ? r3 : __expf(r3) - 1.f;
    if (OUT_BF16) {
        us4 o; o.x = f2bf(r0); o.y = f2bf(r1); o.z = f2bf(r2); o.w = f2bf(r3);
        *(us4*)&((unsigned short*)outv)[(size_t)n * D + lane * 4] = o;
    } else {
        *(float4*)&((float*)outv)[(size_t)n * D + lane * 4] = make_float4(r0, r1, r2, r3);
    }
}

// ---------------- launch ----------------
extern "C" void kernel_launch(void* const* d_in, const int* in_sizes, int n_in,
                              void* d_out, int out_size, void* d_ws, size_t ws_size,
                              hipStream_t stream) {
    const float* x        = (const float*)d_in[0];
    const int*   eidx     = (const int*)d_in[1];
    const float* W1       = (const float*)d_in[2];
    const float* att_src1 = (const float*)d_in[3];
    const float* att_dst1 = (const float*)d_in[4];
    const float* b1       = (const float*)d_in[5];
    const float* W2       = (const float*)d_in[6];
    const float* att_src2 = (const float*)d_in[7];
    const float* att_dst2 = (const float*)d_in[8];
    const float* b2       = (const float*)d_in[9];
    float* out = (float*)d_out;

    char* ws = (char*)d_ws;
    size_t o = 0;
    auto take = [&](size_t bytes) { char* p = ws + o; o = (o + bytes + 255) & ~(size_t)255; return p; };
    float*          h     = (float*)take((size_t)N_NODES * D * 4);          // 51.2 MB (both layers)
    unsigned short* xb    = (unsigned short*)take((size_t)N_NODES * 128 * 2); // 12.8 MB
    unsigned short* zb    = (unsigned short*)take((size_t)N_NODES * D * 2);   // 25.6 MB
    unsigned short* W1t   = (unsigned short*)take((size_t)D * 128 * 2);
    unsigned short* W2t   = (unsigned short*)take((size_t)D * D * 2);
    float*          alpha = (float*)take((size_t)ET * 8 * 4);               // 27.2 MB
    float* es1  = (float*)take((size_t)N_NODES * 8 * 4);
    float* ed1  = (float*)take((size_t)N_NODES * 8 * 4);
    float* es2  = (float*)take((size_t)N_NODES * 4);
    float* ed2  = (float*)take((size_t)N_NODES * 4);
    int*   off  = (int*)take((size_t)(N_NODES + 1) * 4);
    int*   cur  = (int*)take((size_t)N_NODES * 4);
    int*   srcs = (int*)take((size_t)ET * 4);
    int*   deg  = (int*)take((size_t)N_NODES * 4);
    int*   bsum = (int*)take(256);
    int*   carry= (int*)take(256);
    int*   flag = (int*)take(256);

    hipMemsetAsync(deg, 0, (size_t)N_NODES * 4, stream);
    hipMemsetAsync(flag, 0, 4, stream);

    const int EB = (ET + 255) / 256;
    detect_fmt<<<4, 256, 0, stream>>>(eidx, flag);
    count_deg<<<EB, 256, 0, stream>>>(eidx, flag, deg);
    scan_block_sums<<<NB_SCAN, 256, 0, stream>>>(deg, bsum);
    scan_carry<<<1, 64, 0, stream>>>(bsum, carry, off);
    scan_write<<<NB_SCAN, 256, 0, stream>>>(deg, carry, off, cur);
    scatter_edges<<<EB, 256, 0, stream>>>(eidx, flag, cur, srcs);

    // bf16 conversions
    conv_f32_bf16<<<(N_NODES * 128 / 4 + 255) / 256, 256, 0, stream>>>(x, xb, N_NODES * 128 / 4);
    conv_w_t<<<128, 256, 0, stream>>>(W1, W1t, 128);
    conv_w_t<<<256, 256, 0, stream>>>(W2, W2t, 256);

    const int NBLK = (N_NODES + 3) / 4;
    // ---- layer 1 ----
    gemm_bf16<<<dim3(4, (N_NODES + 127) / 128), 256, 0, stream>>>(xb, W1t, h, N_NODES, 128);
    attn_scores<8><<<NBLK, 256, 0, stream>>>(h, att_src1, att_dst1, es1, ed1);
    softmax_alpha<8><<<NBLK, 256, 0, stream>>>(es1, ed1, off, srcs, alpha);
    gather_agg<8, true><<<NBLK, 256, 0, stream>>>(h, alpha, off, srcs, b1, zb);
    // ---- layer 2 ----
    gemm_bf16<<<dim3(4, (N_NODES + 127) / 128), 256, 0, stream>>>(zb, W2t, h, N_NODES, 256);
    attn_scores<1><<<NBLK, 256, 0, stream>>>(h, att_src2, att_dst2, es2, ed2);
    softmax_alpha<1><<<NBLK, 256, 0, stream>>>(es2, ed2, off, srcs, alpha);
    gather_agg<1, false><<<NBLK, 256, 0, stream>>>(h, alpha, off, srcs, b2, out);
}

// Round 3
// 345.682 us; speedup vs baseline: 2.2040x; 1.3457x over previous
//
#include <hip/hip_runtime.h>
#include <math.h>

#define N_NODES 50000
#define N_EDGES 800000
#define ET (N_EDGES + N_NODES)   // 850000 edges incl. self-loops
#define D 256
#define NEG_SLOPE 0.2f
#define SCAN_ITEMS 1024
#define NB_SCAN ((N_NODES + SCAN_ITEMS - 1) / SCAN_ITEMS)   // 49

typedef __attribute__((ext_vector_type(8))) _Float16 half8;     // MFMA A/B frag (8 f16)
typedef __attribute__((ext_vector_type(8))) unsigned short ushort8;
typedef __attribute__((ext_vector_type(4))) unsigned short us4;
typedef __attribute__((ext_vector_type(4))) float f32x4;

__device__ inline unsigned short f2h(float f) {
    union { _Float16 h; unsigned short u; } v; v.h = (_Float16)f; return v.u;
}
__device__ inline float h2f(unsigned short u) {
    union { unsigned short u; _Float16 h; } v; v.u = u; return (float)v.h;
}

// ---------------- edge format probe (int32 vs int64 edge_index) ----------------
__global__ void detect_fmt(const int* __restrict__ eidx, int* __restrict__ flag) {
    int i = blockIdx.x * 256 + threadIdx.x;
    if (i < 1024 && eidx[2 * i + 1] != 0) atomicOr(flag, 1);  // nonzero odd word -> int32
}

__device__ inline int edge_src(const int* eidx, int is32, int e) {
    if (e >= N_EDGES) return e - N_EDGES;
    return is32 ? eidx[e] : eidx[2 * e];
}
__device__ inline int edge_dst(const int* eidx, int is32, int e) {
    if (e >= N_EDGES) return e - N_EDGES;
    return is32 ? eidx[N_EDGES + e] : eidx[2 * (N_EDGES + e)];
}

// ---------------- CSR build ----------------
__global__ void count_deg(const int* __restrict__ eidx, const int* __restrict__ flag,
                          int* __restrict__ deg) {
    int e = blockIdx.x * 256 + threadIdx.x;
    if (e >= ET) return;
    int is32 = *flag;
    atomicAdd(&deg[edge_dst(eidx, is32, e)], 1);
}

__global__ __launch_bounds__(256) void scan_block_sums(const int* __restrict__ deg,
                                                       int* __restrict__ bsum) {
    __shared__ int wsums[4];
    int base = blockIdx.x * SCAN_ITEMS + threadIdx.x * 4;
    int s = 0;
    #pragma unroll
    for (int k = 0; k < 4; ++k) { int i = base + k; if (i < N_NODES) s += deg[i]; }
    for (int d = 1; d < 64; d <<= 1) s += __shfl_xor(s, d, 64);
    int lane = threadIdx.x & 63, wid = threadIdx.x >> 6;
    if (lane == 0) wsums[wid] = s;
    __syncthreads();
    if (threadIdx.x == 0) bsum[blockIdx.x] = wsums[0] + wsums[1] + wsums[2] + wsums[3];
}

__global__ void scan_carry(const int* __restrict__ bsum, int* __restrict__ carry,
                           int* __restrict__ off) {
    if (threadIdx.x == 0) {
        int run = 0;
        for (int b = 0; b < NB_SCAN; ++b) { carry[b] = run; run += bsum[b]; }
        off[N_NODES] = ET;
    }
}

__global__ __launch_bounds__(256) void scan_write(const int* __restrict__ deg,
                                                  const int* __restrict__ carry,
                                                  int* __restrict__ off,
                                                  int* __restrict__ cur) {
    __shared__ int wsums[4];
    int base = blockIdx.x * SCAN_ITEMS + threadIdx.x * 4;
    int v[4]; int s = 0;
    #pragma unroll
    for (int k = 0; k < 4; ++k) { int i = base + k; v[k] = (i < N_NODES) ? deg[i] : 0; s += v[k]; }
    int inc = s;
    int lane = threadIdx.x & 63, wid = threadIdx.x >> 6;
    for (int d = 1; d < 64; d <<= 1) { int u = __shfl_up(inc, d, 64); if (lane >= d) inc += u; }
    if (lane == 63) wsums[wid] = inc;
    __syncthreads();
    int woff = 0;
    for (int w = 0; w < wid; ++w) woff += wsums[w];
    int excl = woff + inc - s + carry[blockIdx.x];
    #pragma unroll
    for (int k = 0; k < 4; ++k) {
        int i = base + k;
        if (i < N_NODES) { off[i] = excl; cur[i] = excl; excl += v[k]; }
    }
}

__global__ void scatter_edges(const int* __restrict__ eidx, const int* __restrict__ flag,
                              int* __restrict__ cur, int* __restrict__ srcs) {
    int e = blockIdx.x * 256 + threadIdx.x;
    if (e >= ET) return;
    int is32 = *flag;
    int src = edge_src(eidx, is32, e);
    int dst = edge_dst(eidx, is32, e);
    int pos = atomicAdd(&cur[dst], 1);
    srcs[pos] = src;
}

// ---------------- conversions ----------------
__global__ __launch_bounds__(256) void conv_f32_f16(const float* __restrict__ in,
                                                    unsigned short* __restrict__ outh,
                                                    int n4) {
    int i = blockIdx.x * 256 + threadIdx.x;
    if (i >= n4) return;
    float4 v = *(const float4*)&in[(size_t)i * 4];
    us4 o; o.x = f2h(v.x); o.y = f2h(v.y); o.z = f2h(v.z); o.w = f2h(v.w);
    *(us4*)&outh[(size_t)i * 4] = o;
}

// W[K][256] -> Wt[256][K] f16
__global__ void conv_w_t(const float* __restrict__ W, unsigned short* __restrict__ Wt, int K) {
    int k = blockIdx.x, n = threadIdx.x;
    Wt[(size_t)n * K + k] = f2h(W[(size_t)k * D + n]);
}

// ---------------- f16 MFMA GEMM: C[M x 256] = A[M x K] * Bt^T, C stored f16 ----------------
__global__ __launch_bounds__(256) void gemm_f16(const unsigned short* __restrict__ A,
                                                const unsigned short* __restrict__ Bt,
                                                unsigned short* __restrict__ C, int M, int K) {
    __shared__ __align__(16) unsigned short As[128][40];  // [row][k], pad to 40
    __shared__ __align__(16) unsigned short Bs[64][40];   // [n][k]
    int t = threadIdx.x, lane = t & 63, wid = t >> 6;
    int wm = wid >> 1, wn = wid & 1;                      // 2x2 waves, wave tile 64x32
    int row0 = blockIdx.y * 128, col0 = blockIdx.x * 64;
    f32x4 acc[4][2] = {};
    int ar = t >> 1, ap = t & 1;                          // A: 2 thr/row, 32B each
    int bn = t >> 2, bp = t & 3;                          // B: 4 thr/row, 16B each
    for (int k0 = 0; k0 < K; k0 += 32) {
        ushort8 a0 = {0,0,0,0,0,0,0,0}, a1 = {0,0,0,0,0,0,0,0};
        if (row0 + ar < M) {
            const ushort8* p = (const ushort8*)&A[(size_t)(row0 + ar) * K + k0 + ap * 16];
            a0 = p[0]; a1 = p[1];
        }
        *(ushort8*)&As[ar][ap * 16]     = a0;
        *(ushort8*)&As[ar][ap * 16 + 8] = a1;
        *(ushort8*)&Bs[bn][bp * 8] = *(const ushort8*)&Bt[(size_t)(col0 + bn) * K + k0 + bp * 8];
        __syncthreads();
        half8 af[4], bg[2];
        #pragma unroll
        for (int mi = 0; mi < 4; ++mi)
            af[mi] = *(const half8*)&As[wm * 64 + mi * 16 + (lane & 15)][(lane >> 4) * 8];
        #pragma unroll
        for (int ni = 0; ni < 2; ++ni)
            bg[ni] = *(const half8*)&Bs[wn * 32 + ni * 16 + (lane & 15)][(lane >> 4) * 8];
        #pragma unroll
        for (int mi = 0; mi < 4; ++mi)
            #pragma unroll
            for (int ni = 0; ni < 2; ++ni)
                acc[mi][ni] = __builtin_amdgcn_mfma_f32_16x16x32_f16(af[mi], bg[ni], acc[mi][ni], 0, 0, 0);
        __syncthreads();
    }
    #pragma unroll
    for (int mi = 0; mi < 4; ++mi) {
        int rowb = row0 + wm * 64 + mi * 16 + ((lane >> 4) << 2);
        #pragma unroll
        for (int ni = 0; ni < 2; ++ni) {
            int col = col0 + wn * 32 + ni * 16 + (lane & 15);
            #pragma unroll
            for (int r = 0; r < 4; ++r)
                if (rowb + r < M) C[(size_t)(rowb + r) * D + col] = f2h(acc[mi][ni][r]);
        }
    }
}

// ---------------- attention scores from f16 h ----------------
template <int HEADS>
__global__ __launch_bounds__(256) void attn_scores(const unsigned short* __restrict__ h,
                                                   const float* __restrict__ a_src,
                                                   const float* __restrict__ a_dst,
                                                   float* __restrict__ es,
                                                   float* __restrict__ ed) {
    int node = blockIdx.x * 4 + (threadIdx.x >> 6);
    int lane = threadIdx.x & 63;
    if (node >= N_NODES) return;
    us4 v = *(const us4*)&h[(size_t)node * D + lane * 4];
    float4 as = *(const float4*)&a_src[lane * 4];
    float4 ad = *(const float4*)&a_dst[lane * 4];
    float vx = h2f(v.x), vy = h2f(v.y), vz = h2f(v.z), vw = h2f(v.w);
    float ps = vx * as.x + vy * as.y + vz * as.z + vw * as.w;
    float pd = vx * ad.x + vy * ad.y + vz * ad.z + vw * ad.w;
    const int GS = 64 / HEADS;
    #pragma unroll
    for (int d2 = 1; d2 < GS; d2 <<= 1) {
        ps += __shfl_xor(ps, d2, 64);
        pd += __shfl_xor(pd, d2, 64);
    }
    if ((lane & (GS - 1)) == 0) {
        int hd = lane / GS;
        es[(size_t)node * HEADS + hd] = ps;
        ed[(size_t)node * HEADS + hd] = pd;
    }
}

// ---------------- per-edge alpha via online softmax; one wave per node ----------------
template <int H>
__global__ __launch_bounds__(256) void softmax_alpha(const float* __restrict__ es,
                                                     const float* __restrict__ ed,
                                                     const int* __restrict__ off,
                                                     const int* __restrict__ srcs,
                                                     float* __restrict__ alpha) {
    int n = blockIdx.x * 4 + (threadIdx.x >> 6);
    if (n >= N_NODES) return;
    int lane = threadIdx.x & 63;
    int begin = off[n], end = off[n + 1];
    int j  = (H == 8) ? (lane >> 3) : lane;
    int hd = (H == 8) ? (lane & 7) : 0;
    const int JS = (H == 8) ? 8 : 64;
    float edn = ed[(size_t)n * H + hd];
    float m = -1e30f, s = 0.f;
    for (int i = begin + j; i < end; i += JS) {
        float e = es[(size_t)srcs[i] * H + hd] + edn;
        e = e > 0.f ? e : NEG_SLOPE * e;
        float nm = fmaxf(m, e);
        s = s * __expf(m - nm) + __expf(e - nm);
        m = nm;
    }
    #pragma unroll
    for (int mask = (H == 8) ? 8 : 1; mask < 64; mask <<= 1) {
        float om = __shfl_xor(m, mask, 64);
        float os = __shfl_xor(s, mask, 64);
        float nm = fmaxf(m, om);
        s = s * __expf(m - nm) + os * __expf(om - nm);
        m = nm;
    }
    float inv_s = 1.f / s;
    for (int i = begin + j; i < end; i += JS) {
        float e = es[(size_t)srcs[i] * H + hd] + edn;
        e = e > 0.f ? e : NEG_SLOPE * e;
        alpha[(size_t)i * H + hd] = __expf(e - m) * inv_s;
    }
}

// ---------------- weighted gather of f16 h + bias + elu; one wave per node ----------------
template <int H, bool OUT_F16>
__global__ __launch_bounds__(256) void gather_agg(const unsigned short* __restrict__ h,
                                                  const float* __restrict__ alpha,
                                                  const int* __restrict__ off,
                                                  const int* __restrict__ srcs,
                                                  const float* __restrict__ bias,
                                                  void* __restrict__ outv) {
    int n = blockIdx.x * 4 + (threadIdx.x >> 6);
    if (n >= N_NODES) return;
    int lane = threadIdx.x & 63;
    int begin = off[n], end = off[n + 1];
    int hsel = (H == 8) ? (lane >> 3) : 0;
    float ax = 0.f, ay = 0.f, az = 0.f, aw = 0.f;
    int i = begin;
    for (; i + 3 < end; i += 4) {
        int s0 = srcs[i], s1 = srcs[i + 1], s2 = srcs[i + 2], s3 = srcs[i + 3];
        float w0 = alpha[(size_t)i * H + hsel];
        float w1 = alpha[(size_t)(i + 1) * H + hsel];
        float w2 = alpha[(size_t)(i + 2) * H + hsel];
        float w3 = alpha[(size_t)(i + 3) * H + hsel];
        us4 v0 = *(const us4*)&h[(size_t)s0 * D + lane * 4];
        us4 v1 = *(const us4*)&h[(size_t)s1 * D + lane * 4];
        us4 v2 = *(const us4*)&h[(size_t)s2 * D + lane * 4];
        us4 v3 = *(const us4*)&h[(size_t)s3 * D + lane * 4];
        ax += h2f(v0.x) * w0 + h2f(v1.x) * w1 + h2f(v2.x) * w2 + h2f(v3.x) * w3;
        ay += h2f(v0.y) * w0 + h2f(v1.y) * w1 + h2f(v2.y) * w2 + h2f(v3.y) * w3;
        az += h2f(v0.z) * w0 + h2f(v1.z) * w1 + h2f(v2.z) * w2 + h2f(v3.z) * w3;
        aw += h2f(v0.w) * w0 + h2f(v1.w) * w1 + h2f(v2.w) * w2 + h2f(v3.w) * w3;
    }
    for (; i < end; ++i) {
        int s0 = srcs[i];
        float w0 = alpha[(size_t)i * H + hsel];
        us4 v0 = *(const us4*)&h[(size_t)s0 * D + lane * 4];
        ax += h2f(v0.x) * w0; ay += h2f(v0.y) * w0; az += h2f(v0.z) * w0; aw += h2f(v0.w) * w0;
    }
    float4 b = *(const float4*)&bias[lane * 4];
    float r0 = ax + b.x, r1 = ay + b.y, r2 = az + b.z, r3 = aw + b.w;
    r0 = r0 > 0.f ? r0 : __expf(r0) - 1.f;
    r1 = r1 > 0.f ? r1 : __expf(r1) - 1.f;
    r2 = r2 > 0.f ? r2 : __expf(r2) - 1.f;
    r3 = r3 > 0.f ? r3 : __expf(r3) - 1.f;
    if (OUT_F16) {
        us4 o; o.x = f2h(r0); o.y = f2h(r1); o.z = f2h(r2); o.w = f2h(r3);
        *(us4*)&((unsigned short*)outv)[(size_t)n * D + lane * 4] = o;
    } else {
        *(float4*)&((float*)outv)[(size_t)n * D + lane * 4] = make_float4(r0, r1, r2, r3);
    }
}

// ---------------- launch ----------------
extern "C" void kernel_launch(void* const* d_in, const int* in_sizes, int n_in,
                              void* d_out, int out_size, void* d_ws, size_t ws_size,
                              hipStream_t stream) {
    const float* x        = (const float*)d_in[0];
    const int*   eidx     = (const int*)d_in[1];
    const float* W1       = (const float*)d_in[2];
    const float* att_src1 = (const float*)d_in[3];
    const float* att_dst1 = (const float*)d_in[4];
    const float* b1       = (const float*)d_in[5];
    const float* W2       = (const float*)d_in[6];
    const float* att_src2 = (const float*)d_in[7];
    const float* att_dst2 = (const float*)d_in[8];
    const float* b2       = (const float*)d_in[9];
    float* out = (float*)d_out;

    char* ws = (char*)d_ws;
    size_t o = 0;
    auto take = [&](size_t bytes) { char* p = ws + o; o = (o + bytes + 255) & ~(size_t)255; return p; };
    unsigned short* hb    = (unsigned short*)take((size_t)N_NODES * D * 2);   // 25.6 MB
    unsigned short* xb    = (unsigned short*)take((size_t)N_NODES * 128 * 2); // 12.8 MB
    unsigned short* zb    = (unsigned short*)take((size_t)N_NODES * D * 2);   // 25.6 MB
    unsigned short* W1t   = (unsigned short*)take((size_t)D * 128 * 2);
    unsigned short* W2t   = (unsigned short*)take((size_t)D * D * 2);
    float*          alpha = (float*)take((size_t)ET * 8 * 4);                 // 27.2 MB
    float* es1  = (float*)take((size_t)N_NODES * 8 * 4);
    float* ed1  = (float*)take((size_t)N_NODES * 8 * 4);
    float* es2  = (float*)take((size_t)N_NODES * 4);
    float* ed2  = (float*)take((size_t)N_NODES * 4);
    int*   off  = (int*)take((size_t)(N_NODES + 1) * 4);
    int*   cur  = (int*)take((size_t)N_NODES * 4);
    int*   srcs = (int*)take((size_t)ET * 4);
    int*   deg  = (int*)take((size_t)N_NODES * 4);
    int*   bsum = (int*)take(256);
    int*   carry= (int*)take(256);
    int*   flag = (int*)take(256);

    hipMemsetAsync(deg, 0, (size_t)N_NODES * 4, stream);
    hipMemsetAsync(flag, 0, 4, stream);

    const int EB = (ET + 255) / 256;
    detect_fmt<<<4, 256, 0, stream>>>(eidx, flag);
    count_deg<<<EB, 256, 0, stream>>>(eidx, flag, deg);
    scan_block_sums<<<NB_SCAN, 256, 0, stream>>>(deg, bsum);
    scan_carry<<<1, 64, 0, stream>>>(bsum, carry, off);
    scan_write<<<NB_SCAN, 256, 0, stream>>>(deg, carry, off, cur);
    scatter_edges<<<EB, 256, 0, stream>>>(eidx, flag, cur, srcs);

    // f16 conversions
    conv_f32_f16<<<(N_NODES * 128 / 4 + 255) / 256, 256, 0, stream>>>(x, xb, N_NODES * 128 / 4);
    conv_w_t<<<128, 256, 0, stream>>>(W1, W1t, 128);
    conv_w_t<<<256, 256, 0, stream>>>(W2, W2t, 256);

    const int NBLK = (N_NODES + 3) / 4;
    // ---- layer 1 ----
    gemm_f16<<<dim3(4, (N_NODES + 127) / 128), 256, 0, stream>>>(xb, W1t, hb, N_NODES, 128);
    attn_scores<8><<<NBLK, 256, 0, stream>>>(hb, att_src1, att_dst1, es1, ed1);
    softmax_alpha<8><<<NBLK, 256, 0, stream>>>(es1, ed1, off, srcs, alpha);
    gather_agg<8, true><<<NBLK, 256, 0, stream>>>(hb, alpha, off, srcs, b1, zb);
    // ---- layer 2 ----
    gemm_f16<<<dim3(4, (N_NODES + 127) / 128), 256, 0, stream>>>(zb, W2t, hb, N_NODES, 256);
    attn_scores<1><<<NBLK, 256, 0, stream>>>(hb, att_src2, att_dst2, es2, ed2);
    softmax_alpha<1><<<NBLK, 256, 0, stream>>>(es2, ed2, off, srcs, alpha);
    gather_agg<1, false><<<NBLK, 256, 0, stream>>>(hb, alpha, off, srcs, b2, out);
}